// Round 2
// baseline (829.932 us; speedup 1.0000x reference)
//
#include <hip/hip_runtime.h>
#include <hip/hip_bf16.h>

// MLPPredictor: score[e][c] = dot(concat(h[src[e]], h[dst[e]], edge_h[e]), W[c]) + b[c]
// E=600000, D=128, EDIM=128, C=10.
// Round 2: software-pipelined K-loop. Tile j+1's global loads are issued into
// registers BEFORE tile j's compute phase, hiding gather latency behind the
// 320-FMA compute block. Same LDS staging / xor-swizzle / scalar-weight
// structure as round 1 (byte counts were already at the floor).

#define E_PER_BLOCK 256
#define KT 32            // features per tile
#define NTILE 12         // 384 / 32
#define NC 10

__global__ __launch_bounds__(256, 4) void mlp_edge_kernel(
    const float* __restrict__ h,      // [N,128]
    const float* __restrict__ eh,     // [E,128]
    const float* __restrict__ Ww,     // [10,384]
    const float* __restrict__ Wb,     // [10]
    const int*   __restrict__ src,    // [E]
    const int*   __restrict__ dst,    // [E]
    float* __restrict__ out,          // [E,10]
    int E)
{
    __shared__ float tile[E_PER_BLOCK][KT];   // 32 KB, xor-swizzled float4 chunks
    __shared__ int s_sh[E_PER_BLOCK];
    __shared__ int d_sh[E_PER_BLOCK];

    const int tid = threadIdx.x;
    const long blockStart = (long)blockIdx.x * E_PER_BLOCK;
    const long myE = blockStart + tid;

    // stage src/dst indices for the whole block (guard tail with 0)
    {
        int s = 0, d = 0;
        if (myE < E) { s = src[myE]; d = dst[myE]; }
        s_sh[tid] = s;
        d_sh[tid] = d;
    }
    __syncthreads();

    // accumulators init = bias (uniform scalar loads)
    float acc[NC];
#pragma unroll
    for (int c = 0; c < NC; ++c) acc[c] = Wb[c];

    const int quad  = tid & 7;    // float4 slot within a 32-float row segment
    const int rbase = tid >> 3;   // 0..31

    // ---- prefetch registers: next tile's 8 x float4 per thread ----
    float4 pre[8];

    // address generator for tile j, sub-row i (uniform branches on j)
    auto issue_tile = [&](int j) {
        const int kg = j * KT;
#pragma unroll
        for (int i = 0; i < 8; ++i) {
            const int row = i * 32 + rbase;
            const float* gsrc;
            if (j < 4) {
                gsrc = h + (long)s_sh[row] * 128 + (kg + quad * 4);
            } else if (j < 8) {
                gsrc = h + (long)d_sh[row] * 128 + ((kg - 128) + quad * 4);
            } else {
                const long er = blockStart + row;
                const long ec = (er < E) ? er : (long)(E - 1);
                gsrc = eh + ec * 128 + ((kg - 256) + quad * 4);
            }
            pre[i] = *(const float4*)gsrc;   // in-flight until ds_write next iter
        }
    };

    issue_tile(0);

#pragma unroll 1
    for (int j = 0; j < NTILE; ++j) {
        const int kg = j * KT;    // uniform

        // ---- LDS is free (previous compute done); commit prefetched tile ----
        // (compiler inserts the vmcnt wait right before the first ds_write)
#pragma unroll
        for (int i = 0; i < 8; ++i) {
            const int row = i * 32 + rbase;
            const int sq = quad ^ (row & 7);          // xor swizzle chunk
            *(float4*)&tile[row][sq * 4] = pre[i];
        }
        __syncthreads();

        // ---- issue NEXT tile's loads now; they fly during this compute ----
        if (j + 1 < NTILE) issue_tile(j + 1);

        // ---- consume own row: 8 x float4, FMA vs scalar (s_load) weights ----
#pragma unroll
        for (int k4 = 0; k4 < 8; ++k4) {
            const int sq = k4 ^ (tid & 7);
            const float4 f = *(const float4*)&tile[tid][sq * 4];
#pragma unroll
            for (int c = 0; c < NC; ++c) {
                const float* w = Ww + c * 384 + kg + k4 * 4;  // uniform -> s_load
                acc[c] = fmaf(f.x, w[0], acc[c]);
                acc[c] = fmaf(f.y, w[1], acc[c]);
                acc[c] = fmaf(f.z, w[2], acc[c]);
                acc[c] = fmaf(f.w, w[3], acc[c]);
            }
        }
        __syncthreads();   // LDS free for next iteration's ds_write
    }

    // ---- store 10 outputs per edge; 40B/edge -> five float2 stores ----
    if (myE < E) {
        float* o = out + myE * NC;
#pragma unroll
        for (int c = 0; c < NC; c += 2) {
            float2 v;
            v.x = acc[c];
            v.y = acc[c + 1];
            *(float2*)(o + c) = v;
        }
    }
}

extern "C" void kernel_launch(void* const* d_in, const int* in_sizes, int n_in,
                              void* d_out, int out_size, void* d_ws, size_t ws_size,
                              hipStream_t stream) {
    const float* h   = (const float*)d_in[0];
    const float* eh  = (const float*)d_in[1];
    const float* Ww  = (const float*)d_in[2];
    const float* Wb  = (const float*)d_in[3];
    const int*   src = (const int*)d_in[4];
    const int*   dst = (const int*)d_in[5];
    float* out = (float*)d_out;

    const int E = in_sizes[4];
    const int blocks = (E + E_PER_BLOCK - 1) / E_PER_BLOCK;
    mlp_edge_kernel<<<blocks, E_PER_BLOCK, 0, stream>>>(h, eh, Ww, Wb, src, dst, out, E);
}

// Round 3
// 522.426 us; speedup vs baseline: 1.5886x; 1.5886x over previous
//
#include <hip/hip_runtime.h>
#include <hip/hip_bf16.h>

// MLPPredictor: score[e][c] = dot(concat(h[src[e]], h[dst[e]], edge_h[e]), W[c]) + b[c]
// E=600000, D=128, EDIM=128, C=10.
// Round 3: round-2's pipeline idea, but spill-proof. Round 2's pre[8] array
// (in a lambda, live across a barrier) went to scratch: WRITE_SIZE 23->880 MB
// == 600k threads x 11 tiles x 128 B. Fix: individual named float4 p0..p7 and
// named per-chunk offsets (no arrays, no lambda). Also block 256->128:
// 17 KB LDS -> 9 blocks/CU (vs 4), cheaper 2-wave barriers.

#define EPB   128        // edges per block == threads per block
#define KT    32         // features per tile
#define NTILE 12         // 384 / 32
#define NC    10

__global__ __launch_bounds__(EPB, 4) void mlp_edge_kernel(
    const float* __restrict__ h,      // [N,128]
    const float* __restrict__ eh,     // [E,128]
    const float* __restrict__ Ww,     // [10,384]
    const float* __restrict__ Wb,     // [10]
    const int*   __restrict__ src,    // [E]
    const int*   __restrict__ dst,    // [E]
    float* __restrict__ out,          // [E,10]
    int E)
{
    __shared__ __align__(128) float tile[EPB][KT];   // 16 KB, xor-swizzled float4 chunks
    __shared__ int s_sh[EPB];
    __shared__ int d_sh[EPB];

    const int tid = threadIdx.x;
    const long blockStart = (long)blockIdx.x * EPB;
    const long myE = blockStart + tid;

    // stage src/dst indices for the whole block (tail -> 0, reads h[0] harmlessly)
    {
        int s = 0, d = 0;
        if (myE < E) { s = src[myE]; d = dst[myE]; }
        s_sh[tid] = s;
        d_sh[tid] = d;
    }
    __syncthreads();

    const int quad  = tid & 7;            // float4 slot within a 32-float segment
    const int rbase = tid >> 3;           // 0..15
    const int q4    = quad * 4;
    const int swc   = (quad ^ (rbase & 7)) * 4;   // swizzled write column (floats)

    // Per-chunk (i=0..7) source offsets as NAMED scalars. Indices read from
    // LDS once, here, so the K-loop's address gen has no lgkm dependency.
#define DEFROW(i) \
    const int  row##i = (i) * 16 + rbase; \
    const int  hs##i  = s_sh[row##i] * 128 + q4; \
    const int  hd##i  = d_sh[row##i] * 128 + q4; \
    const long ee##i  = blockStart + row##i; \
    const long he##i  = ((ee##i < E) ? ee##i : (long)(E - 1)) * 128 + q4;
    DEFROW(0) DEFROW(1) DEFROW(2) DEFROW(3)
    DEFROW(4) DEFROW(5) DEFROW(6) DEFROW(7)
#undef DEFROW

    float acc[NC];                         // statically indexed -> registers
#pragma unroll
    for (int c = 0; c < NC; ++c) acc[c] = Wb[c];

    // prefetch registers: individual named variables, never an array
    float4 p0, p1, p2, p3, p4, p5, p6, p7;

#define ISSUE(jn) do {                                            \
    if ((jn) < 4) {                                               \
        const int ko = (jn) * KT;                                 \
        p0 = *(const float4*)(h + hs0 + ko);                      \
        p1 = *(const float4*)(h + hs1 + ko);                      \
        p2 = *(const float4*)(h + hs2 + ko);                      \
        p3 = *(const float4*)(h + hs3 + ko);                      \
        p4 = *(const float4*)(h + hs4 + ko);                      \
        p5 = *(const float4*)(h + hs5 + ko);                      \
        p6 = *(const float4*)(h + hs6 + ko);                      \
        p7 = *(const float4*)(h + hs7 + ko);                      \
    } else if ((jn) < 8) {                                        \
        const int ko = ((jn) - 4) * KT;                           \
        p0 = *(const float4*)(h + hd0 + ko);                      \
        p1 = *(const float4*)(h + hd1 + ko);                      \
        p2 = *(const float4*)(h + hd2 + ko);                      \
        p3 = *(const float4*)(h + hd3 + ko);                      \
        p4 = *(const float4*)(h + hd4 + ko);                      \
        p5 = *(const float4*)(h + hd5 + ko);                      \
        p6 = *(const float4*)(h + hd6 + ko);                      \
        p7 = *(const float4*)(h + hd7 + ko);                      \
    } else {                                                      \
        const int ko = ((jn) - 8) * KT;                           \
        p0 = *(const float4*)(eh + he0 + ko);                     \
        p1 = *(const float4*)(eh + he1 + ko);                     \
        p2 = *(const float4*)(eh + he2 + ko);                     \
        p3 = *(const float4*)(eh + he3 + ko);                     \
        p4 = *(const float4*)(eh + he4 + ko);                     \
        p5 = *(const float4*)(eh + he5 + ko);                     \
        p6 = *(const float4*)(eh + he6 + ko);                     \
        p7 = *(const float4*)(eh + he7 + ko);                     \
    } } while (0)

    ISSUE(0);

#pragma unroll 1
    for (int j = 0; j < NTILE; ++j) {
        // commit prefetched tile to LDS (vmcnt wait inserted right here)
        *(float4*)&tile[row0][swc] = p0;
        *(float4*)&tile[row1][swc] = p1;
        *(float4*)&tile[row2][swc] = p2;
        *(float4*)&tile[row3][swc] = p3;
        *(float4*)&tile[row4][swc] = p4;
        *(float4*)&tile[row5][swc] = p5;
        *(float4*)&tile[row6][swc] = p6;
        *(float4*)&tile[row7][swc] = p7;
        __syncthreads();

        // issue NEXT tile's loads; they fly during this tile's 320 FMAs
        if (j + 1 < NTILE) ISSUE(j + 1);

        const int kg = j * KT;             // uniform
#pragma unroll
        for (int k4 = 0; k4 < 8; ++k4) {
            const int sq = (k4 ^ quad) * 4;
            const float4 f = *(const float4*)&tile[tid][sq];
#pragma unroll
            for (int c = 0; c < NC; ++c) {
                const float* w = Ww + c * 384 + kg + k4 * 4;   // uniform -> s_load
                acc[c] = fmaf(f.x, w[0], acc[c]);
                acc[c] = fmaf(f.y, w[1], acc[c]);
                acc[c] = fmaf(f.z, w[2], acc[c]);
                acc[c] = fmaf(f.w, w[3], acc[c]);
            }
        }
        __syncthreads();
    }
#undef ISSUE

    // store 10 outputs per edge; 40 B/edge -> five float2 stores
    if (myE < E) {
        float* o = out + myE * NC;
#pragma unroll
        for (int c = 0; c < NC; c += 2) {
            float2 v;
            v.x = acc[c];
            v.y = acc[c + 1];
            *(float2*)(o + c) = v;
        }
    }
}

extern "C" void kernel_launch(void* const* d_in, const int* in_sizes, int n_in,
                              void* d_out, int out_size, void* d_ws, size_t ws_size,
                              hipStream_t stream) {
    const float* h   = (const float*)d_in[0];
    const float* eh  = (const float*)d_in[1];
    const float* Ww  = (const float*)d_in[2];
    const float* Wb  = (const float*)d_in[3];
    const int*   src = (const int*)d_in[4];
    const int*   dst = (const int*)d_in[5];
    float* out = (float*)d_out;

    const int E = in_sizes[4];
    const int blocks = (E + EPB - 1) / EPB;
    mlp_edge_kernel<<<blocks, EPB, 0, stream>>>(h, eh, Ww, Wb, src, dst, out, E);
}

// Round 4
// 488.382 us; speedup vs baseline: 1.6993x; 1.0697x over previous
//
#include <hip/hip_runtime.h>

// MLPPredictor as a bf16 MFMA GEMM: C[E,10] = concat(h[src],h[dst],eh)[E,384] x W^T + b
// Round 4: round-3 showed the per-thread-FMA design stalls on mixed DS+SMEM
// lgkmcnt drains (VALUBusy 19%) and 24 block barriers. New structure:
//  - 1 wave = 1 block = 16 edges (tile M=16, N=16 (10 used), K=384 = 12 MFMA).
//  - Weights live in 48 VGPRs as B-fragments (built once per block from L1-hot
//    Ww) -> NO loads of any kind inside the K-loop.
//  - Single-wave block => __syncthreads is wave-local, no inter-wave coupling.
//  - LDS rows padded 384->392 ushorts (stride 196 dwords == 4 mod 32) ->
//    only 2-way bank aliasing on b128 reads (free per m136).
// bf16 precision: expected absmax ~1e-2 vs threshold 1.09e-1.

typedef __attribute__((ext_vector_type(8))) short    short8;
typedef __attribute__((ext_vector_type(4))) float    f32x4;
typedef __attribute__((ext_vector_type(4))) unsigned short us4;

#define NC    10
#define EPW   16          // edges per (single-wave) block
#define ROWUS 392         // ushorts per LDS row: 384 data + 8 pad  (784 B)

__device__ __forceinline__ unsigned short f2bf(float f) {
    unsigned u = __builtin_bit_cast(unsigned, f);
    u += 0x7FFFu + ((u >> 16) & 1u);          // round-to-nearest-even
    return (unsigned short)(u >> 16);
}

__global__ __launch_bounds__(64, 4) void mlp_edge_mfma(
    const float* __restrict__ h,      // [N,128]
    const float* __restrict__ eh,     // [E,128]
    const float* __restrict__ Ww,     // [10,384]
    const float* __restrict__ Wb,     // [10]
    const int*   __restrict__ src,    // [E]
    const int*   __restrict__ dst,    // [E]
    float* __restrict__ out,          // [E,10]
    int E)
{
    __shared__ __align__(16) unsigned short lds[EPW * ROWUS];   // 12544 B

    const int  l    = threadIdx.x;          // 0..63
    const long base = (long)blockIdx.x * EPW;
    const int  n    = l & 15;               // MFMA column (class)
    const int  q    = l >> 4;               // 0..3 (k-quad)
    const int  r8   = l & ~0 ? (l >> 3) : 0;// 0..7: staging row within group
    const int  c8   = l & 7;                // staging 16B-chunk within 128B seg

    // ---- edge indices for my two staging rows ----
    const long eA  = base + (l >> 3);
    const long eB  = base + 8 + (l >> 3);
    const long eAc = (eA < E) ? eA : (long)(E - 1);
    const long eBc = (eB < E) ? eB : (long)(E - 1);
    const int  sA = src[eAc], sB = src[eBc];
    const int  dA = dst[eAc], dB = dst[eBc];

    // ---- B fragments: lane holds W[n][t*32 + q*8 .. +8] as bf16 (zero n>=10)
    short8 bf[12];
#pragma unroll
    for (int t = 0; t < 12; ++t) bf[t] = (short8)0;
    if (n < NC) {
        const float* wr = Ww + n * 384 + q * 8;
#pragma unroll
        for (int t = 0; t < 12; ++t) {
            const f32x4 w0 = *(const f32x4*)(wr + t * 32);
            const f32x4 w1 = *(const f32x4*)(wr + t * 32 + 4);
            short8 b;
            b[0] = (short)f2bf(w0[0]); b[1] = (short)f2bf(w0[1]);
            b[2] = (short)f2bf(w0[2]); b[3] = (short)f2bf(w0[3]);
            b[4] = (short)f2bf(w1[0]); b[5] = (short)f2bf(w1[1]);
            b[6] = (short)f2bf(w1[2]); b[7] = (short)f2bf(w1[3]);
            bf[t] = b;
        }
    }

    // ---- stage 16 rows x 384 floats (3 sources) as bf16 into LDS ----
    // Per source: rows rA=(l>>3), rB=8+(l>>3); seg = 128B segment of the row.
    // Coalesced: 8 lanes cover one 128B line per row per seg.
#define STAGE(gaddrA, gaddrB, so) do {                                        \
    _Pragma("unroll")                                                         \
    for (int seg = 0; seg < 4; ++seg) {                                       \
        const f32x4 va = *(const f32x4*)((gaddrA) + seg * 32 + c8 * 4);       \
        const f32x4 vb = *(const f32x4*)((gaddrB) + seg * 32 + c8 * 4);       \
        us4 ua, ub;                                                           \
        ua[0]=f2bf(va[0]); ua[1]=f2bf(va[1]); ua[2]=f2bf(va[2]); ua[3]=f2bf(va[3]); \
        ub[0]=f2bf(vb[0]); ub[1]=f2bf(vb[1]); ub[2]=f2bf(vb[2]); ub[3]=f2bf(vb[3]); \
        *(us4*)&lds[(l >> 3) * ROWUS + (so) + seg * 32 + c8 * 4]       = ua;  \
        *(us4*)&lds[((l >> 3) + 8) * ROWUS + (so) + seg * 32 + c8 * 4] = ub;  \
    } } while (0)

    STAGE(h  + (long)sA * 128, h  + (long)sB * 128, 0);    // k 0..127  : h[src]
    STAGE(h  + (long)dA * 128, h  + (long)dB * 128, 128);  // k 128..255: h[dst]
    STAGE(eh + eAc * 128,      eh + eBc * 128,      256);  // k 256..383: edge_h
#undef STAGE

    __syncthreads();   // single-wave block: compiles to a local waitcnt

    // ---- 12 MFMA steps over K=384; A-frag: row n, k = t*32 + q*8 ----
    f32x4 acc = {0.f, 0.f, 0.f, 0.f};
    const unsigned short* arow = &lds[n * ROWUS + q * 8];
#pragma unroll
    for (int t = 0; t < 12; ++t) {
        const short8 af = *(const short8*)(arow + t * 32);
        acc = __builtin_amdgcn_mfma_f32_16x16x32_bf16(af, bf[t], acc, 0, 0, 0);
    }

    // ---- epilogue: C/D layout col=n=lane&15, row(edge) = q*4 + reg ----
    if (n < NC) {
        const float bias = Wb[n];
#pragma unroll
        for (int r = 0; r < 4; ++r) {
            const long e = base + q * 4 + r;
            if (e < E) out[e * NC + n] = acc[r] + bias;
        }
    }
}

extern "C" void kernel_launch(void* const* d_in, const int* in_sizes, int n_in,
                              void* d_out, int out_size, void* d_ws, size_t ws_size,
                              hipStream_t stream) {
    const float* h   = (const float*)d_in[0];
    const float* eh  = (const float*)d_in[1];
    const float* Ww  = (const float*)d_in[2];
    const float* Wb  = (const float*)d_in[3];
    const int*   src = (const int*)d_in[4];
    const int*   dst = (const int*)d_in[5];
    float* out = (float*)d_out;

    const int E = in_sizes[4];
    const int blocks = (E + EPW - 1) / EPW;   // 37500 for E=600000
    mlp_edge_mfma<<<blocks, 64, 0, stream>>>(h, eh, Ww, Wb, src, dst, out, E);
}